// Round 5
// baseline (463.468 us; speedup 1.0000x reference)
//
#include <hip/hip_runtime.h>
#include <hip/hip_bf16.h>

typedef __hip_bfloat16 bf16;
typedef __attribute__((ext_vector_type(8))) short s16x8;   // 8 bf16 (4 VGPRs) MFMA frag
typedef __attribute__((ext_vector_type(4))) float f32x4;   // MFMA accumulator

#define B_ 2
#define S_ 4096
#define H_ 2048
#define R_ 2048
#define M_ 8192      // B*S
#define NB_ 16
#define BW_ 128
#define CHUNK 64     // scan chunk length
#define NCH 64       // S/CHUNK

__device__ __forceinline__ short f2b_s(float f) {
    return (short)__builtin_bit_cast(unsigned short, __float2bfloat16(f));
}
__device__ __forceinline__ float b2f_s(short s) {
    unsigned int u = ((unsigned int)(unsigned short)s) << 16;
    return __builtin_bit_cast(float, u);
}
__device__ __forceinline__ float sigm_fast(float x) { return 1.f / (1.f + __expf(-x)); }

// async global->LDS, 16B per lane; LDS dest must be wave-uniform base + lane*16
__device__ __forceinline__ void async_g2l(const void* g, void* l) {
    __builtin_amdgcn_global_load_lds((const __attribute__((address_space(1))) void*)g,
                                     (__attribute__((address_space(3))) void*)l, 16, 0, 0);
}

// ---------------- merged cast fp32 -> bf16 for x / Wxy / Wres ----------------
__global__ __launch_bounds__(256) void cast_all(const float* __restrict__ x,
                                                const float* __restrict__ wxy,
                                                const float* __restrict__ wres,
                                                bf16* __restrict__ xbf,
                                                bf16* __restrict__ wxyb,
                                                bf16* __restrict__ wresb) {
    int idx = blockIdx.x * 256 + threadIdx.x;
    const float* in; bf16* out; int off;
    if (idx < 2097152)      { in = x;    out = xbf;   off = idx; }
    else if (idx < 3145728) { in = wxy;  out = wxyb;  off = idx - 2097152; }
    else                    { in = wres; out = wresb; off = idx - 3145728; }
    size_t i8 = (size_t)off * 8;
    float4 v0 = *(const float4*)(in + i8);
    float4 v1 = *(const float4*)(in + i8 + 4);
    s16x8 o;
    o[0] = f2b_s(v0.x); o[1] = f2b_s(v0.y); o[2] = f2b_s(v0.z); o[3] = f2b_s(v0.w);
    o[4] = f2b_s(v1.x); o[5] = f2b_s(v1.y); o[6] = f2b_s(v1.z); o[7] = f2b_s(v1.w);
    *(s16x8*)(out + i8) = o;
}

// ---------------- transpose-cast gate weights via LDS tile ----------------
__global__ __launch_bounds__(256) void wcast_T(const float* __restrict__ igw,
                                               const float* __restrict__ agw,
                                               bf16* __restrict__ wT) {
    __shared__ float tile[128 * 129];
    int blk = blockIdx.x;
    int p = blk >> 4, n = blk & 15;
    const float* w = (p ? agw : igw) + (size_t)n * 16384;   // [i][j] row-major
    int tid = threadIdx.x;
#pragma unroll
    for (int it = 0; it < 64; ++it) {
        int u = it * 256 + tid;           // element: i = u>>7, j = u&127
        tile[(u >> 7) * 129 + (u & 127)] = w[u];
    }
    __syncthreads();
    bf16* o = wT + (size_t)blk * 16384;
#pragma unroll
    for (int it = 0; it < 64; ++it) {
        int u = it * 256 + tid;           // output elem: j = u>>7, i = u&127
        o[u] = __float2bfloat16(tile[(u & 127) * 129 + (u >> 7)]);
    }
}

// ---------------- sp8[r] = 8*softplus(a_param[r]) ----------------
__global__ __launch_bounds__(256) void sp8_kernel(const float* __restrict__ apar,
                                                  float* __restrict__ sp8) {
    int r = blockIdx.x * 256 + threadIdx.x;
    float ap = apar[r];
    sp8[r] = 8.f * (ap > 20.f ? ap : log1pf(expf(ap)));
}

// ---------------- generic NT GEMM: C[M,N] = A[M,K] * B[N,K]^T, bf16 in, OutT out ----
// 128x128 tile, BK=64, 4 waves 2x2, 64x64/wave, 16x16x32 MFMA, XOR-swizzled LDS,
// global_load_lds width=16 staging. launch_bounds(256,4): 4 blocks/CU.
// R0-proven: 126.5 us GEMM1 (1084 TF, MfmaUtil 52%, 0 conflicts). R1-R4's 256^2
// deep-pipeline port topped at 955 TF (acc=128 VGPR -> 2 waves/SIMD, 1 block/CU:
// every barrier is a full-CU stall; this kernel's 4 blocks/CU hide latency better).
__device__ __forceinline__ void store_c(float* p, float v) { *p = v; }
__device__ __forceinline__ void store_c(bf16* p, float v) { *p = __float2bfloat16(v); }

template <typename OutT>
__global__ __launch_bounds__(256, 4) void gemm_bt(const bf16* __restrict__ A,
                                                  const bf16* __restrict__ Bm,
                                                  OutT* __restrict__ C,
                                                  int K, int lda, int ldb, int ldc) {
    __shared__ __align__(16) short As[128 * 64];
    __shared__ __align__(16) short Bs[128 * 64];
    const int tid = threadIdx.x;
    const int lane = tid & 63, wave = tid >> 6;
    const int waveM = wave >> 1, waveN = wave & 1;
    const int mBase = blockIdx.y * 128, nBase = blockIdx.x * 128;
    const int fm = lane & 15, q = lane >> 4;

    f32x4 acc[4][4];
#pragma unroll
    for (int i = 0; i < 4; ++i)
#pragma unroll
        for (int j = 0; j < 4; ++j) acc[i][j] = (f32x4){0.f, 0.f, 0.f, 0.f};

    for (int k0 = 0; k0 < K; k0 += 64) {
        __syncthreads();
#pragma unroll
        for (int it = 0; it < 4; ++it) {
            int off = it * 4096 + tid * 16;          // byte offset in tile (lane-contig)
            int r = off >> 7;                        // row
            int g = ((off & 127) >> 4) ^ (r & 7);    // source k-group for this slot
            async_g2l(A + (size_t)(mBase + r) * lda + k0 + g * 8, (char*)As + off);
            async_g2l(Bm + (size_t)(nBase + r) * ldb + k0 + g * 8, (char*)Bs + off);
        }
        __syncthreads();
#pragma unroll
        for (int s = 0; s < 2; ++s) {
            s16x8 af[4], bfr[4];
#pragma unroll
            for (int i = 0; i < 4; ++i) {
                int row = waveM * 64 + i * 16 + fm;
                af[i] = *(const s16x8*)((char*)As + row * 128 + ((((s << 2) + q) ^ (row & 7)) << 4));
                int col = waveN * 64 + i * 16 + fm;
                bfr[i] = *(const s16x8*)((char*)Bs + col * 128 + ((((s << 2) + q) ^ (col & 7)) << 4));
            }
#pragma unroll
            for (int i = 0; i < 4; ++i)
#pragma unroll
                for (int j = 0; j < 4; ++j)
                    acc[i][j] = __builtin_amdgcn_mfma_f32_16x16x32_bf16(af[i], bfr[j], acc[i][j], 0, 0, 0);
        }
    }
    // C/D layout: col=lane&15, row=q*4+reg (m89/m91-verified)
#pragma unroll
    for (int i = 0; i < 4; ++i) {
        int rowg = mBase + waveM * 64 + i * 16 + q * 4;
#pragma unroll
        for (int j = 0; j < 4; ++j) {
            int colg = nBase + waveN * 64 + j * 16 + fm;
#pragma unroll
            for (int rr = 0; rr < 4; ++rr)
                store_c(C + (size_t)(rowg + rr) * ldc + colg, acc[i][j][rr]);
        }
    }
}

// ------- fused: causal conv + block-diag dual gate GEMM + RG-LRU + chunk scan -------
// grid (NB_, M_/64): one block = one (batch, 64-step chunk, 128-channel block).
// R5 change: instead of emitting (la, nx) for passB to RE-RUN the recurrence,
// phase 6 emits the running per-chunk state (hloc_t, cum_t) directly ->
// h_full(t) = hloc_t + cum_t * carry. Same bytes written; passB turns elementwise.
__global__ __launch_bounds__(256) void gate_kernel(const bf16* __restrict__ xy,
                                                   const float* __restrict__ cw,
                                                   const float* __restrict__ cb,
                                                   const bf16* __restrict__ wT,
                                                   const float* __restrict__ igb,
                                                   const float* __restrict__ agb,
                                                   const float* __restrict__ sp8,
                                                   bf16* __restrict__ hloc_out,
                                                   bf16* __restrict__ cum_out,
                                                   float* __restrict__ Ach,
                                                   float* __restrict__ Hla) {
    __shared__ __align__(16) short As[64 * 128];     // 16 KB; xc tile -> nx tile
    __shared__ __align__(16) char  Wmem[128 * 256];  // 32 KB; Xs raw -> W tile -> a[64][128] f32
    short* Xs   = (short*)Wmem;                      // 67 rows x 128 shorts (raw xy window)
    short* Ws   = (short*)Wmem;
    float* a_sh = (float*)Wmem;
    const int n = blockIdx.x;
    const int mBase = blockIdx.y * 64;
    const int tid = threadIdx.x;
    const int lane = tid & 63, wave = tid >> 6;
    const int fm = lane & 15, q = lane >> 4;
    const int t0 = mBase & (S_ - 1);

    // 1. stage xy window: rows rr=0..66 <-> m = mBase + rr - 3 (zero outside batch)
#pragma unroll
    for (int it = 0; it < 5; ++it) {
        int u = it * 256 + tid;              // (rr, gg): rr = u>>4, gg = u&15
        if (u < 67 * 16) {
            int rr = u >> 4, gg = u & 15;
            s16x8 v = (s16x8){0, 0, 0, 0, 0, 0, 0, 0};
            if (t0 != 0 || rr >= 3) {
                int m = mBase + rr - 3;
                v = *(const s16x8*)(xy + (size_t)m * 4096 + n * BW_ + gg * 8);
            }
            *(s16x8*)((char*)Xs + u * 16) = v;
        }
    }
    __syncthreads();

    // 2. conv into As (swizzled bf16): thread = (col, row-half), sliding 4-tap window
    {
        int col = tid & 127, rh = tid >> 7;
        int rbase = n * BW_ + col;
        float w0c = cw[rbase], w1c = cw[R_ + rbase], w2c = cw[2 * R_ + rbase],
              w3c = cw[3 * R_ + rbase];
        float bc = cb[rbase];
        int r0 = rh * 32;
        float xm3 = b2f_s(Xs[(r0 + 0) * 128 + col]);
        float xm2 = b2f_s(Xs[(r0 + 1) * 128 + col]);
        float xm1 = b2f_s(Xs[(r0 + 2) * 128 + col]);
#pragma unroll
        for (int rw = 0; rw < 32; ++rw) {
            int row = r0 + rw;
            float x0 = b2f_s(Xs[(row + 3) * 128 + col]);
            float v = bc + w0c * xm3 + w1c * xm2 + w2c * xm1 + w3c * x0;
            xm3 = xm2; xm2 = xm1; xm1 = x0;
            *(short*)((char*)As + row * 256 + ((((col >> 3)) ^ (row & 15)) << 4) +
                      (col & 7) * 2) = f2b_s(v);
        }
    }
    __syncthreads();   // As ready; Xs region dead

    // 3. stage Ws for input gate
    const bf16* w0 = wT + (size_t)n * 16384;
#pragma unroll
    for (int it = 0; it < 8; ++it) {
        int off = it * 4096 + tid * 16;
        int j = off >> 8;
        int g = ((off & 255) >> 4) ^ (j & 15);
        async_g2l(w0 + j * 128 + g * 8, (char*)Ws + off);
    }
    __syncthreads();

    f32x4 accI[8], accA[8];
#pragma unroll
    for (int jj = 0; jj < 8; ++jj) {
        accI[jj] = (f32x4){0.f, 0.f, 0.f, 0.f};
        accA[jj] = (f32x4){0.f, 0.f, 0.f, 0.f};
    }

    const int row = wave * 16 + fm;
#pragma unroll
    for (int s = 0; s < 4; ++s) {
        s16x8 af = *(const s16x8*)((char*)As + row * 256 + ((((s << 2) + q) ^ (row & 15)) << 4));
#pragma unroll
        for (int jj = 0; jj < 8; ++jj) {
            int wrow = jj * 16 + fm;
            s16x8 bw = *(const s16x8*)((char*)Ws + wrow * 256 + ((((s << 2) + q) ^ (wrow & 15)) << 4));
            accI[jj] = __builtin_amdgcn_mfma_f32_16x16x32_bf16(af, bw, accI[jj], 0, 0, 0);
        }
    }
    __syncthreads();  // all waves done reading Ws (gate 1)
    // 4. stage Ws for a gate
    const bf16* w1 = wT + (size_t)(NB_ + n) * 16384;
#pragma unroll
    for (int it = 0; it < 8; ++it) {
        int off = it * 4096 + tid * 16;
        int j = off >> 8;
        int g = ((off & 255) >> 4) ^ (j & 15);
        async_g2l(w1 + j * 128 + g * 8, (char*)Ws + off);
    }
    __syncthreads();
#pragma unroll
    for (int s = 0; s < 4; ++s) {
        s16x8 af = *(const s16x8*)((char*)As + row * 256 + ((((s << 2) + q) ^ (row & 15)) << 4));
#pragma unroll
        for (int jj = 0; jj < 8; ++jj) {
            int wrow = jj * 16 + fm;
            s16x8 bw = *(const s16x8*)((char*)Ws + wrow * 256 + ((((s << 2) + q) ^ (wrow & 15)) << 4));
            accA[jj] = __builtin_amdgcn_mfma_f32_16x16x32_bf16(af, bw, accA[jj], 0, 0, 0);
        }
    }
    __syncthreads();  // MFMA reads of As/Ws done; epilogue may overwrite both

    // 5. epilogue: C/D col=fm, row=q*4+rr. a into a_sh; nx into own As slot.
    //    (no global writes here anymore -- phase 6 emits hloc/cum instead)
#pragma unroll
    for (int jj = 0; jj < 8; ++jj) {
        int col = jj * 16 + fm;
        int r = n * BW_ + col;
        float bi = igb[r], ba = agb[r];
        float s8 = sp8[r];
#pragma unroll
        for (int rr = 0; rr < 4; ++rr) {
            int rowl = wave * 16 + q * 4 + rr;
            short* slot = (short*)((char*)As + rowl * 256 +
                          ((((col >> 3)) ^ (rowl & 15)) << 4) + (col & 7) * 2);
            float xcv = b2f_s(*slot);
            float xg = accI[jj][rr] + bi;
            float ag = accA[jj][rr] + ba;
            float la = -s8 * sigm_fast(ag);
            float av = __expf(la);
            float t2 = 2.f * la;
            float nem = (t2 > -0.125f)
                ? -t2 * (1.f + t2 * (0.5f + t2 * (0.16666667f + t2 * 0.04166667f)))
                : 1.f - av * av;
            float nxv = xcv * sigm_fast(xg) * sqrtf(nem);
            short nxs = f2b_s(nxv);
            a_sh[rowl * 128 + col] = av;
            *slot = nxs;                       // same slot this thread read; no race
        }
    }
    __syncthreads();

    // 6. fused chunk scan: threads 0..127, one channel each, sequential over 64 rows.
    //    Emits running state per t: hloc_t (h with zero carry), cum_t (prod of a).
    if (tid < 128) {
        int col = tid;
        float h = 0.f, cum = 1.f;
        size_t o = (size_t)mBase * R_ + n * BW_ + col;
#pragma unroll 4
        for (int t = 0; t < CHUNK; ++t) {
            float a = a_sh[t * 128 + col];
            float nxv = b2f_s(*(const short*)((char*)As + t * 256 +
                              ((((col >> 3)) ^ (t & 15)) << 4) + (col & 7) * 2));
            h = fmaf(a, h, nxv);
            cum *= a;
            hloc_out[o] = __float2bfloat16(h);
            cum_out[o]  = __float2bfloat16(cum);
            o += R_;
        }
        int b = mBase >> 12, c = (mBase & (S_ - 1)) >> 6;
        int so = ((b * NCH + c) << 11) + n * BW_ + col;
        Ach[so] = cum;
        Hla[so] = h;
    }
}

// carry into each chunk (sequential over 64 chunks, fp32)
__global__ __launch_bounds__(256) void scan_carry(const float* __restrict__ Ach,
                                                  const float* __restrict__ Hla,
                                                  float* __restrict__ carry) {
    int idx = blockIdx.x * 256 + threadIdx.x;  // B*R
    int r = idx & (R_ - 1), b = idx >> 11;
    float cy = 0.f;
#pragma unroll 4
    for (int c = 0; c < NCH; ++c) {
        int o = (b * NCH + c) * R_ + r;
        carry[o] = cy;
        cy = fmaf(Ach[o], cy, Hla[o]);
    }
}

// passB (R5: elementwise): h_full = hloc + cum*carry; g = gelu_exact(y)*h_full -> bf16.
// 8 consecutive r per thread (vectorized loads, G13). No serial recurrence, no exp.
__global__ __launch_bounds__(256) void scan_passB(const bf16* __restrict__ hloc,
                                                  const bf16* __restrict__ cum,
                                                  const float* __restrict__ carry,
                                                  const bf16* __restrict__ xy,
                                                  bf16* __restrict__ g_out) {
    int idx = blockIdx.x * 256 + threadIdx.x;   // M*R/8 = 2097152 units
    int m = idx >> 8;                           // row
    int r = (idx & 255) << 3;                   // col*8
    int b = m >> 12, c = (m & 4095) >> 6;
    int so = ((b * NCH + c) << 11) + r;
    size_t o = (size_t)m * R_ + r;
    s16x8 hv = *(const s16x8*)(hloc + o);
    s16x8 cv = *(const s16x8*)(cum + o);
    float4 cy0 = *(const float4*)(carry + so);
    float4 cy1 = *(const float4*)(carry + so + 4);
    s16x8 yv = *(const s16x8*)(xy + (size_t)m * 4096 + 2048 + r);
    float cya0 = cy0.x, cya1 = cy0.y, cya2 = cy0.z, cya3 = cy0.w;
    float cya4 = cy1.x, cya5 = cy1.y, cya6 = cy1.z, cya7 = cy1.w;
    s16x8 g;
#pragma unroll 8
    for (int i = 0; i < 8; ++i) {
        float cy = (i == 0) ? cya0 : (i == 1) ? cya1 : (i == 2) ? cya2 : (i == 3) ? cya3
                 : (i == 4) ? cya4 : (i == 5) ? cya5 : (i == 6) ? cya6 : cya7;
        float h = fmaf(b2f_s(cv[i]), cy, b2f_s(hv[i]));
        float y = b2f_s(yv[i]);
        float gg = 0.5f * y * (1.f + erff(y * 0.70710678f));
        g[i] = f2b_s(gg * h);
    }
    *(s16x8*)(g_out + o) = g;
}

extern "C" void kernel_launch(void* const* d_in, const int* in_sizes, int n_in,
                              void* d_out, int out_size, void* d_ws, size_t ws_size,
                              hipStream_t stream) {
    const float* x    = (const float*)d_in[0];
    const float* Wxy  = (const float*)d_in[1];
    const float* igw  = (const float*)d_in[2];
    const float* igb  = (const float*)d_in[3];
    const float* agw  = (const float*)d_in[4];
    const float* agb  = (const float*)d_in[5];
    const float* apar = (const float*)d_in[6];
    const float* cw   = (const float*)d_in[7];
    const float* cb   = (const float*)d_in[8];
    const float* Wres = (const float*)d_in[9];
    float* out = (float*)d_out;

    // Workspace (187 MiB), lifetime overlays:
    //   [0,32)    xbf  bf16 [M,H]   (dead after GEMM1)  -> hloc bf16 [M,R]
    //   [32,48)   wxyb bf16 [2R,H]  (dead after GEMM1)  -> wT (1 MiB) + sp8
    //   [48,112)  xy   bf16 [M,4096] (xr|y); xr dead after gate, y until passB
    //   [112,120) wresb bf16
    //   [120,152) g    bf16 [M,R]  (passB output)
    //   [152,184) cum  bf16 [M,R]
    //   [184,187) Ach/Hla/carry fp32, 1 MiB each
    char* ws = (char*)d_ws;
    const size_t MiB = (size_t)1 << 20;
    bf16*  xbf   = (bf16*)(ws);
    bf16*  hloc  = (bf16*)(ws);               // overlay on xbf
    bf16*  wxyb  = (bf16*)(ws + 32 * MiB);
    bf16*  wT    = (bf16*)(ws + 32 * MiB);    // overlay (staged after GEMM1)
    float* sp8   = (float*)(ws + 33 * MiB + 65536);
    bf16*  xy    = (bf16*)(ws + 48 * MiB);
    bf16*  wresb = (bf16*)(ws + 112 * MiB);
    bf16*  g     = (bf16*)(ws + 120 * MiB);
    bf16*  cum   = (bf16*)(ws + 152 * MiB);
    float* Ach   = (float*)(ws + 184 * MiB);
    float* Hla   = (float*)(ws + 185 * MiB);
    float* cyb   = (float*)(ws + 186 * MiB);

    // merged casts to bf16
    cast_all<<<14336, 256, 0, stream>>>(x, Wxy, Wres, xbf, wxyb, wresb);

    // GEMM1 (merged): xy[M,4096] = x[M,2048] * Wxy[4096,2048]^T
    gemm_bt<bf16><<<dim3(32, 64), 256, 0, stream>>>(xbf, wxyb, xy, 2048, 2048, 2048, 4096);

    // gate prep (after GEMM1 so wT/sp8 can overlay wxyb)
    wcast_T<<<32, 256, 0, stream>>>(igw, agw, wT);
    sp8_kernel<<<8, 256, 0, stream>>>(apar, sp8);

    // fused conv + gates + chunk summaries -> hloc (overlays xbf), cum, Ach, Hla
    gate_kernel<<<dim3(NB_, 128), 256, 0, stream>>>(xy, cw, cb, wT, igb, agb, sp8,
                                                    hloc, cum, Ach, Hla);

    // carry scan + elementwise passB -> g
    scan_carry<<<16, 256, 0, stream>>>(Ach, Hla, cyb);
    scan_passB<<<8192, 256, 0, stream>>>(hloc, cum, cyb, xy, g);

    // GEMM2: out[M,H] = g[M,R] * Wres[H,R]^T  (fp32 out)
    gemm_bt<float><<<dim3(16, 64), 256, 0, stream>>>(g, wresb, out, 2048, 2048, 2048, 2048);
}

// Round 6
// 455.898 us; speedup vs baseline: 1.0166x; 1.0166x over previous
//
#include <hip/hip_runtime.h>
#include <hip/hip_bf16.h>

typedef __hip_bfloat16 bf16;
typedef __attribute__((ext_vector_type(8))) short s16x8;   // 8 bf16 (4 VGPRs) MFMA frag
typedef __attribute__((ext_vector_type(4))) float f32x4;   // MFMA accumulator

#define B_ 2
#define S_ 4096
#define H_ 2048
#define R_ 2048
#define M_ 8192      // B*S
#define NB_ 16
#define BW_ 128
#define CHUNK 64     // scan chunk length
#define NCH 64       // S/CHUNK

__device__ __forceinline__ short f2b_s(float f) {
    return (short)__builtin_bit_cast(unsigned short, __float2bfloat16(f));
}
__device__ __forceinline__ float b2f_s(short s) {
    unsigned int u = ((unsigned int)(unsigned short)s) << 16;
    return __builtin_bit_cast(float, u);
}
__device__ __forceinline__ float sigm_fast(float x) { return 1.f / (1.f + __expf(-x)); }

// async global->LDS, 16B per lane; LDS dest must be wave-uniform base + lane*16
__device__ __forceinline__ void async_g2l(const void* g, void* l) {
    __builtin_amdgcn_global_load_lds((const __attribute__((address_space(1))) void*)g,
                                     (__attribute__((address_space(3))) void*)l, 16, 0, 0);
}

// ---------------- merged cast fp32 -> bf16 for x / Wxy / Wres ----------------
__global__ __launch_bounds__(256) void cast_all(const float* __restrict__ x,
                                                const float* __restrict__ wxy,
                                                const float* __restrict__ wres,
                                                bf16* __restrict__ xbf,
                                                bf16* __restrict__ wxyb,
                                                bf16* __restrict__ wresb) {
    int idx = blockIdx.x * 256 + threadIdx.x;
    const float* in; bf16* out; int off;
    if (idx < 2097152)      { in = x;    out = xbf;   off = idx; }
    else if (idx < 3145728) { in = wxy;  out = wxyb;  off = idx - 2097152; }
    else                    { in = wres; out = wresb; off = idx - 3145728; }
    size_t i8 = (size_t)off * 8;
    float4 v0 = *(const float4*)(in + i8);
    float4 v1 = *(const float4*)(in + i8 + 4);
    s16x8 o;
    o[0] = f2b_s(v0.x); o[1] = f2b_s(v0.y); o[2] = f2b_s(v0.z); o[3] = f2b_s(v0.w);
    o[4] = f2b_s(v1.x); o[5] = f2b_s(v1.y); o[6] = f2b_s(v1.z); o[7] = f2b_s(v1.w);
    *(s16x8*)(out + i8) = o;
}

// ---------------- transpose-cast gate weights via LDS tile ----------------
__global__ __launch_bounds__(256) void wcast_T(const float* __restrict__ igw,
                                               const float* __restrict__ agw,
                                               bf16* __restrict__ wT) {
    __shared__ float tile[128 * 129];
    int blk = blockIdx.x;
    int p = blk >> 4, n = blk & 15;
    const float* w = (p ? agw : igw) + (size_t)n * 16384;   // [i][j] row-major
    int tid = threadIdx.x;
#pragma unroll
    for (int it = 0; it < 64; ++it) {
        int u = it * 256 + tid;           // element: i = u>>7, j = u&127
        tile[(u >> 7) * 129 + (u & 127)] = w[u];
    }
    __syncthreads();
    bf16* o = wT + (size_t)blk * 16384;
#pragma unroll
    for (int it = 0; it < 64; ++it) {
        int u = it * 256 + tid;           // output elem: j = u>>7, i = u&127
        o[u] = __float2bfloat16(tile[(u & 127) * 129 + (u >> 7)]);
    }
}

// ---------------- sp8[r] = 8*softplus(a_param[r]) ----------------
__global__ __launch_bounds__(256) void sp8_kernel(const float* __restrict__ apar,
                                                  float* __restrict__ sp8) {
    int r = blockIdx.x * 256 + threadIdx.x;
    float ap = apar[r];
    sp8[r] = 8.f * (ap > 20.f ? ap : log1pf(expf(ap)));
}

__device__ __forceinline__ void store_c(float* p, float v) { *p = v; }
__device__ __forceinline__ void store_c(bf16* p, float v) { *p = __float2bfloat16(v); }

// ---------------- 256x256 8-phase (2 K-tiles/iter) pipelined NT GEMM ----------------
// C[M,N] = A[M,K]*B[N,K]^T. 8 waves (2M x 4N), per-wave 128x64, BK=64, NT=K/64 (even).
// LDS 128 KiB: buf b=tile&1 (64 KiB): A halves (128 rows x 128 B) at +0/+16384,
// B halves at +32768/+49152. Swizzle = gemm_bt's proven slot^(row&7) (0 conflicts).
// R2-R4 post-mortem: schedules waited vmcnt twice/K-tile with only 2-4 loads allowed
// outstanding -> every stage had <=1200 cyc to land vs ~900 cyc HBM latency ->
// latency-starved at each wait (955 TF). This schedule: ONE vmcnt(4) per K-tile
// (p4/p8), leaving only the 2 newest B-halves outstanding; every staged half gets
// >=3 phases (~1800+ cyc) of flight. STRICTLY race-free stage map (each stage
// targets a region whose last reads drained at an EARLIER phase's lgkmcnt(0)):
//   p1: rd A(Ta,q0)+B(Ta)[12, lgkm8]; stage A0(Tb)      [buf1.A idle since prev p8]
//   p2: rd A(Ta,q1); stage A1(Tb), B0(Ta+2)             [buf0.B dead after p1]
//   p3: rd A(Ta,q2); stage B1(Ta+2)
//   p4: rd A(Ta,q3); vmcnt(4) (t==LT: 0)                [forces A(Tb) landed for p5]
//   p5-p8: mirror on buf1 (stages A0/A1(Ta+2) [buf0.A dead after p4], B0/B1(Tb+2))
// B-frags load once per K-tile (p1/p5) and live in regs through the 4 quadrants.
#define MFMA16(Q)                                                                     \
    _Pragma("unroll") for (int j = 0; j < 4; ++j) {                                   \
        acc[2*(Q)][j]   = __builtin_amdgcn_mfma_f32_16x16x32_bf16(af[0][0], bfr[j][0], acc[2*(Q)][j], 0, 0, 0);   \
        acc[2*(Q)][j]   = __builtin_amdgcn_mfma_f32_16x16x32_bf16(af[0][1], bfr[j][1], acc[2*(Q)][j], 0, 0, 0);   \
        acc[2*(Q)+1][j] = __builtin_amdgcn_mfma_f32_16x16x32_bf16(af[1][0], bfr[j][0], acc[2*(Q)+1][j], 0, 0, 0); \
        acc[2*(Q)+1][j] = __builtin_amdgcn_mfma_f32_16x16x32_bf16(af[1][1], bfr[j][1], acc[2*(Q)+1][j], 0, 0, 0); \
    }

#define PHASE(BASEP, Q, LOADB, STMTS, VMSTMT)                                         \
    rdA2(BASEP, Q, af);                                                               \
    if (LOADB) rdB8(BASEP, bfr);                                                      \
    STMTS;                                                                            \
    if (LOADB) asm volatile("s_waitcnt lgkmcnt(8)" ::: "memory");                     \
    __builtin_amdgcn_s_barrier();                                                     \
    asm volatile("s_waitcnt lgkmcnt(0)" ::: "memory");                                \
    __builtin_amdgcn_sched_barrier(0);                                                \
    __builtin_amdgcn_s_setprio(1);                                                    \
    MFMA16(Q);                                                                        \
    __builtin_amdgcn_s_setprio(0);                                                    \
    VMSTMT;                                                                           \
    __builtin_amdgcn_s_barrier();                                                     \
    __builtin_amdgcn_sched_barrier(0);

template <typename OutT>
__global__ __launch_bounds__(512, 2) void gemm256(const bf16* __restrict__ A,
                                                  const bf16* __restrict__ Bm,
                                                  OutT* __restrict__ C,
                                                  int K, int lda, int ldb, int ldc) {
    extern __shared__ __align__(16) char lds[];
    const int tid = threadIdx.x;
    const int lane = tid & 63, wave = tid >> 6;
    const int wm = wave >> 2, wn = wave & 3;
    const int fm = lane & 15, q = lane >> 4;
    const int mBase = blockIdx.y * 256, nBase = blockIdx.x * 256;
    const int NT = K >> 6, LT = (NT >> 1) - 1;

    // stage half-tile: hh 0:B-half0 1:B-half1 2:A-half0 3:A-half1. 16 KiB =
    // 128 rows x 128 B; LDS dest linear; source k-group pre-permuted g = slot^(r&7).
    auto stage_half = [&](int tile, int hh) {
        if (tile >= NT) return;
        const bf16* src = (hh < 2) ? Bm : A;
        const int ld = (hh < 2) ? ldb : lda;
        const int rowBase = ((hh < 2) ? nBase : mBase) + ((hh & 1) << 7);
        char* dst = lds + ((tile & 1) << 16) + ((hh < 2) ? 32768 : 0) + ((hh & 1) << 14);
#pragma unroll
        for (int rnd = 0; rnd < 2; ++rnd) {
            int off = rnd * 8192 + tid * 16;
            int r = off >> 7;                        // row within half, 0..127
            int g = ((off >> 4) & 7) ^ (r & 7);      // source k-group for this slot
            async_g2l(src + (size_t)(rowBase + r) * ld + tile * 64 + g * 8, dst + off);
        }
    };
    auto rdA2 = [&](const char* base, int qp, s16x8 (&dst)[2][2]) {
#pragma unroll
        for (int i2 = 0; i2 < 2; ++i2) {
            int r7 = (qp * 2 + i2) * 16 + fm;        // row within own half
            const char* p = base + (wm << 14) + r7 * 128;
#pragma unroll
            for (int kk = 0; kk < 2; ++kk)
                dst[i2][kk] = *(const s16x8*)(p + ((((kk << 2) + q) ^ (r7 & 7)) << 4));
        }
    };
    auto rdB8 = [&](const char* base, s16x8 (&dst)[4][2]) {
#pragma unroll
        for (int j = 0; j < 4; ++j) {
            int col = wn * 64 + j * 16 + fm;
            const char* p = base + 32768 + ((col >> 7) << 14) + (col & 127) * 128;
#pragma unroll
            for (int kk = 0; kk < 2; ++kk)
                dst[j][kk] = *(const s16x8*)(p + ((((kk << 2) + q) ^ (col & 7)) << 4));
        }
    };

    s16x8 af[2][2], bfr[4][2];
    f32x4 acc[8][4];
#pragma unroll
    for (int i = 0; i < 8; ++i)
#pragma unroll
        for (int j = 0; j < 4; ++j) acc[i][j] = (f32x4){0.f, 0.f, 0.f, 0.f};

    // prologue: tile0 all 4 halves (oldest), then tile1 B halves. vmcnt(4) forces
    // tile0 landed; tile1's B may stay in flight (forced by p4's vmcnt(4)).
    stage_half(0, 0); stage_half(0, 1); stage_half(0, 2); stage_half(0, 3);
    stage_half(1, 0); stage_half(1, 1);
    asm volatile("s_waitcnt vmcnt(4)" ::: "memory");
    __builtin_amdgcn_s_barrier();
    __builtin_amdgcn_sched_barrier(0);

    for (int t = 0; t <= LT; ++t) {
        const int Ta = 2 * t, Tb = Ta + 1;
        const char* b0 = lds;            // Ta even -> buf0
        const char* b1 = lds + 65536;    // Tb -> buf1

        PHASE(b0, 0, 1, { stage_half(Tb, 2); }, {})
        PHASE(b0, 1, 0, { stage_half(Tb, 3); stage_half(Ta + 2, 0); }, {})
        PHASE(b0, 2, 0, { stage_half(Ta + 2, 1); }, {})
        PHASE(b0, 3, 0, {},
              { if (t < LT) asm volatile("s_waitcnt vmcnt(4)" ::: "memory");
                else        asm volatile("s_waitcnt vmcnt(0)" ::: "memory"); })

        PHASE(b1, 0, 1, { stage_half(Ta + 2, 2); }, {})
        PHASE(b1, 1, 0, { stage_half(Ta + 2, 3); stage_half(Tb + 2, 0); }, {})
        PHASE(b1, 2, 0, { stage_half(Tb + 2, 1); }, {})
        PHASE(b1, 3, 0, {},
              { if (t < LT) asm volatile("s_waitcnt vmcnt(4)" ::: "memory");
                else        asm volatile("s_waitcnt vmcnt(0)" ::: "memory"); })
    }

    // C/D layout: col=lane&15, row=q*4+reg (m89/m91-verified)
#pragma unroll
    for (int i = 0; i < 8; ++i) {
        int rowg = mBase + wm * 128 + i * 16 + q * 4;
#pragma unroll
        for (int j = 0; j < 4; ++j) {
            int colg = nBase + wn * 64 + j * 16 + fm;
#pragma unroll
            for (int rr = 0; rr < 4; ++rr)
                store_c(C + (size_t)(rowg + rr) * ldc + colg, acc[i][j][rr]);
        }
    }
}

// ------- fused: causal conv + block-diag dual gate GEMM + RG-LRU + chunk scan -------
// grid (NB_, M_/64): one block = one (batch, 64-step chunk, 128-channel block).
// Emits running per-chunk state (hloc_t, cum_t): h_full = hloc + cum*carry.
__global__ __launch_bounds__(256) void gate_kernel(const bf16* __restrict__ xy,
                                                   const float* __restrict__ cw,
                                                   const float* __restrict__ cb,
                                                   const bf16* __restrict__ wT,
                                                   const float* __restrict__ igb,
                                                   const float* __restrict__ agb,
                                                   const float* __restrict__ sp8,
                                                   bf16* __restrict__ hloc_out,
                                                   bf16* __restrict__ cum_out,
                                                   float* __restrict__ Ach,
                                                   float* __restrict__ Hla) {
    __shared__ __align__(16) short As[64 * 128];     // 16 KB; xc tile -> nx tile
    __shared__ __align__(16) char  Wmem[128 * 256];  // 32 KB; Xs raw -> W tile -> a[64][128] f32
    short* Xs   = (short*)Wmem;                      // 67 rows x 128 shorts (raw xy window)
    short* Ws   = (short*)Wmem;
    float* a_sh = (float*)Wmem;
    const int n = blockIdx.x;
    const int mBase = blockIdx.y * 64;
    const int tid = threadIdx.x;
    const int lane = tid & 63, wave = tid >> 6;
    const int fm = lane & 15, q = lane >> 4;
    const int t0 = mBase & (S_ - 1);

    // 1. stage xy window: rows rr=0..66 <-> m = mBase + rr - 3 (zero outside batch)
#pragma unroll
    for (int it = 0; it < 5; ++it) {
        int u = it * 256 + tid;              // (rr, gg): rr = u>>4, gg = u&15
        if (u < 67 * 16) {
            int rr = u >> 4, gg = u & 15;
            s16x8 v = (s16x8){0, 0, 0, 0, 0, 0, 0, 0};
            if (t0 != 0 || rr >= 3) {
                int m = mBase + rr - 3;
                v = *(const s16x8*)(xy + (size_t)m * 4096 + n * BW_ + gg * 8);
            }
            *(s16x8*)((char*)Xs + u * 16) = v;
        }
    }
    __syncthreads();

    // 2. conv into As (swizzled bf16): thread = (col, row-half), sliding 4-tap window
    {
        int col = tid & 127, rh = tid >> 7;
        int rbase = n * BW_ + col;
        float w0c = cw[rbase], w1c = cw[R_ + rbase], w2c = cw[2 * R_ + rbase],
              w3c = cw[3 * R_ + rbase];
        float bc = cb[rbase];
        int r0 = rh * 32;
        float xm3 = b2f_s(Xs[(r0 + 0) * 128 + col]);
        float xm2 = b2f_s(Xs[(r0 + 1) * 128 + col]);
        float xm1 = b2f_s(Xs[(r0 + 2) * 128 + col]);
#pragma unroll
        for (int rw = 0; rw < 32; ++rw) {
            int row = r0 + rw;
            float x0 = b2f_s(Xs[(row + 3) * 128 + col]);
            float v = bc + w0c * xm3 + w1c * xm2 + w2c * xm1 + w3c * x0;
            xm3 = xm2; xm2 = xm1; xm1 = x0;
            *(short*)((char*)As + row * 256 + ((((col >> 3)) ^ (row & 15)) << 4) +
                      (col & 7) * 2) = f2b_s(v);
        }
    }
    __syncthreads();   // As ready; Xs region dead

    // 3. stage Ws for input gate
    const bf16* w0 = wT + (size_t)n * 16384;
#pragma unroll
    for (int it = 0; it < 8; ++it) {
        int off = it * 4096 + tid * 16;
        int j = off >> 8;
        int g = ((off & 255) >> 4) ^ (j & 15);
        async_g2l(w0 + j * 128 + g * 8, (char*)Ws + off);
    }
    __syncthreads();

    f32x4 accI[8], accA[8];
#pragma unroll
    for (int jj = 0; jj < 8; ++jj) {
        accI[jj] = (f32x4){0.f, 0.f, 0.f, 0.f};
        accA[jj] = (f32x4){0.f, 0.f, 0.f, 0.f};
    }

    const int row = wave * 16 + fm;
#pragma unroll
    for (int s = 0; s < 4; ++s) {
        s16x8 af = *(const s16x8*)((char*)As + row * 256 + ((((s << 2) + q) ^ (row & 15)) << 4));
#pragma unroll
        for (int jj = 0; jj < 8; ++jj) {
            int wrow = jj * 16 + fm;
            s16x8 bw = *(const s16x8*)((char*)Ws + wrow * 256 + ((((s << 2) + q) ^ (wrow & 15)) << 4));
            accI[jj] = __builtin_amdgcn_mfma_f32_16x16x32_bf16(af, bw, accI[jj], 0, 0, 0);
        }
    }
    __syncthreads();  // all waves done reading Ws (gate 1)
    // 4. stage Ws for a gate
    const bf16* w1 = wT + (size_t)(NB_ + n) * 16384;
#pragma unroll
    for (int it = 0; it < 8; ++it) {
        int off = it * 4096 + tid * 16;
        int j = off >> 8;
        int g = ((off & 255) >> 4) ^ (j & 15);
        async_g2l(w1 + j * 128 + g * 8, (char*)Ws + off);
    }
    __syncthreads();
#pragma unroll
    for (int s = 0; s < 4; ++s) {
        s16x8 af = *(const s16x8*)((char*)As + row * 256 + ((((s << 2) + q) ^ (row & 15)) << 4));
#pragma unroll
        for (int jj = 0; jj < 8; ++jj) {
            int wrow = jj * 16 + fm;
            s16x8 bw = *(const s16x8*)((char*)Ws + wrow * 256 + ((((s << 2) + q) ^ (wrow & 15)) << 4));
            accA[jj] = __builtin_amdgcn_mfma_f32_16x16x32_bf16(af, bw, accA[jj], 0, 0, 0);
        }
    }
    __syncthreads();  // MFMA reads of As/Ws done; epilogue may overwrite both

    // 5. epilogue: C/D col=fm, row=q*4+rr. a into a_sh; nx into own As slot.
#pragma unroll
    for (int jj = 0; jj < 8; ++jj) {
        int col = jj * 16 + fm;
        int r = n * BW_ + col;
        float bi = igb[r], ba = agb[r];
        float s8 = sp8[r];
#pragma unroll
        for (int rr = 0; rr < 4; ++rr) {
            int rowl = wave * 16 + q * 4 + rr;
            short* slot = (short*)((char*)As + rowl * 256 +
                          ((((col >> 3)) ^ (rowl & 15)) << 4) + (col & 7) * 2);
            float xcv = b2f_s(*slot);
            float xg = accI[jj][rr] + bi;
            float ag = accA[jj][rr] + ba;
            float la = -s8 * sigm_fast(ag);
            float av = __expf(la);
            float t2 = 2.f * la;
            float nem = (t2 > -0.125f)
                ? -t2 * (1.f + t2 * (0.5f + t2 * (0.16666667f + t2 * 0.04166667f)))
                : 1.f - av * av;
            float nxv = xcv * sigm_fast(xg) * sqrtf(nem);
            short nxs = f2b_s(nxv);
            a_sh[rowl * 128 + col] = av;
            *slot = nxs;                       // same slot this thread read; no race
        }
    }
    __syncthreads();

    // 6. fused chunk scan: threads 0..127, one channel each, sequential over 64 rows.
    if (tid < 128) {
        int col = tid;
        float h = 0.f, cum = 1.f;
        size_t o = (size_t)mBase * R_ + n * BW_ + col;
#pragma unroll 4
        for (int t = 0; t < CHUNK; ++t) {
            float a = a_sh[t * 128 + col];
            float nxv = b2f_s(*(const short*)((char*)As + t * 256 +
                              ((((col >> 3)) ^ (t & 15)) << 4) + (col & 7) * 2));
            h = fmaf(a, h, nxv);
            cum *= a;
            hloc_out[o] = __float2bfloat16(h);
            cum_out[o]  = __float2bfloat16(cum);
            o += R_;
        }
        int b = mBase >> 12, c = (mBase & (S_ - 1)) >> 6;
        int so = ((b * NCH + c) << 11) + n * BW_ + col;
        Ach[so] = cum;
        Hla[so] = h;
    }
}

// carry into each chunk (sequential over 64 chunks, fp32)
__global__ __launch_bounds__(256) void scan_carry(const float* __restrict__ Ach,
                                                  const float* __restrict__ Hla,
                                                  float* __restrict__ carry) {
    int idx = blockIdx.x * 256 + threadIdx.x;  // B*R
    int r = idx & (R_ - 1), b = idx >> 11;
    float cy = 0.f;
#pragma unroll 4
    for (int c = 0; c < NCH; ++c) {
        int o = (b * NCH + c) * R_ + r;
        carry[o] = cy;
        cy = fmaf(Ach[o], cy, Hla[o]);
    }
}

// passB (elementwise): h_full = hloc + cum*carry; g = gelu_exact(y)*h_full -> bf16.
__global__ __launch_bounds__(256) void scan_passB(const bf16* __restrict__ hloc,
                                                  const bf16* __restrict__ cum,
                                                  const float* __restrict__ carry,
                                                  const bf16* __restrict__ xy,
                                                  bf16* __restrict__ g_out) {
    int idx = blockIdx.x * 256 + threadIdx.x;   // M*R/8 = 2097152 units
    int m = idx >> 8;                           // row
    int r = (idx & 255) << 3;                   // col*8
    int b = m >> 12, c = (m & 4095) >> 6;
    int so = ((b * NCH + c) << 11) + r;
    size_t o = (size_t)m * R_ + r;
    s16x8 hv = *(const s16x8*)(hloc + o);
    s16x8 cv = *(const s16x8*)(cum + o);
    float4 cy0 = *(const float4*)(carry + so);
    float4 cy1 = *(const float4*)(carry + so + 4);
    s16x8 yv = *(const s16x8*)(xy + (size_t)m * 4096 + 2048 + r);
    float cya0 = cy0.x, cya1 = cy0.y, cya2 = cy0.z, cya3 = cy0.w;
    float cya4 = cy1.x, cya5 = cy1.y, cya6 = cy1.z, cya7 = cy1.w;
    s16x8 g;
#pragma unroll 8
    for (int i = 0; i < 8; ++i) {
        float cy = (i == 0) ? cya0 : (i == 1) ? cya1 : (i == 2) ? cya2 : (i == 3) ? cya3
                 : (i == 4) ? cya4 : (i == 5) ? cya5 : (i == 6) ? cya6 : cya7;
        float h = fmaf(b2f_s(cv[i]), cy, b2f_s(hv[i]));
        float y = b2f_s(yv[i]);
        float gg = 0.5f * y * (1.f + erff(y * 0.70710678f));
        g[i] = f2b_s(gg * h);
    }
    *(s16x8*)(g_out + o) = g;
}

extern "C" void kernel_launch(void* const* d_in, const int* in_sizes, int n_in,
                              void* d_out, int out_size, void* d_ws, size_t ws_size,
                              hipStream_t stream) {
    const float* x    = (const float*)d_in[0];
    const float* Wxy  = (const float*)d_in[1];
    const float* igw  = (const float*)d_in[2];
    const float* igb  = (const float*)d_in[3];
    const float* agw  = (const float*)d_in[4];
    const float* agb  = (const float*)d_in[5];
    const float* apar = (const float*)d_in[6];
    const float* cw   = (const float*)d_in[7];
    const float* cb   = (const float*)d_in[8];
    const float* Wres = (const float*)d_in[9];
    float* out = (float*)d_out;

    // Workspace (187 MiB), lifetime overlays:
    //   [0,32)    xbf  bf16 [M,H]   (dead after GEMM1)  -> hloc bf16 [M,R]
    //   [32,48)   wxyb bf16 [2R,H]  (dead after GEMM1)  -> wT (1 MiB) + sp8
    //   [48,112)  xy   bf16 [M,4096] (xr|y); xr dead after gate, y until passB
    //   [112,120) wresb bf16
    //   [120,152) g    bf16 [M,R]  (passB output)
    //   [152,184) cum  bf16 [M,R]
    //   [184,187) Ach/Hla/carry fp32, 1 MiB each
    char* ws = (char*)d_ws;
    const size_t MiB = (size_t)1 << 20;
    bf16*  xbf   = (bf16*)(ws);
    bf16*  hloc  = (bf16*)(ws);               // overlay on xbf
    bf16*  wxyb  = (bf16*)(ws + 32 * MiB);
    bf16*  wT    = (bf16*)(ws + 32 * MiB);    // overlay (staged after GEMM1)
    float* sp8   = (float*)(ws + 33 * MiB + 65536);
    bf16*  xy    = (bf16*)(ws + 48 * MiB);
    bf16*  wresb = (bf16*)(ws + 112 * MiB);
    bf16*  g     = (bf16*)(ws + 120 * MiB);
    bf16*  cum   = (bf16*)(ws + 152 * MiB);
    float* Ach   = (float*)(ws + 184 * MiB);
    float* Hla   = (float*)(ws + 185 * MiB);
    float* cyb   = (float*)(ws + 186 * MiB);

    // merged casts to bf16
    cast_all<<<14336, 256, 0, stream>>>(x, Wxy, Wres, xbf, wxyb, wresb);

    // GEMM1: xy[M,4096] = x[M,2048] * Wxy[4096,2048]^T
    gemm256<bf16><<<dim3(16, 32), 512, 131072, stream>>>(xbf, wxyb, xy, 2048, 2048, 2048, 4096);

    // gate prep (after GEMM1 so wT/sp8 can overlay wxyb)
    wcast_T<<<32, 256, 0, stream>>>(igw, agw, wT);
    sp8_kernel<<<8, 256, 0, stream>>>(apar, sp8);

    // fused conv + gates + chunk summaries -> hloc (overlays xbf), cum, Ach, Hla
    gate_kernel<<<dim3(NB_, 128), 256, 0, stream>>>(xy, cw, cb, wT, igb, agb, sp8,
                                                    hloc, cum, Ach, Hla);

    // carry scan + elementwise passB -> g
    scan_carry<<<16, 256, 0, stream>>>(Ach, Hla, cyb);
    scan_passB<<<8192, 256, 0, stream>>>(hloc, cum, cyb, xy, g);

    // GEMM2: out[M,H] = g[M,R] * Wres[H,R]^T  (fp32 out)
    gemm256<float><<<dim3(8, 32), 512, 131072, stream>>>(g, wresb, out, 2048, 2048, 2048, 2048);
}